// Round 10
// baseline (229.241 us; speedup 1.0000x reference)
//
#include <hip/hip_runtime.h>
#include <hip/hip_bf16.h>

typedef __bf16 bf16_t;
typedef __bf16 bf16x8 __attribute__((ext_vector_type(8)));
typedef float  f32x4  __attribute__((ext_vector_type(4)));
typedef unsigned short ushort_t;

#define MFMA16(a, b, c) __builtin_amdgcn_mfma_f32_16x16x32_bf16((a), (b), (c), 0, 0, 0)
// async global->LDS, 16B/lane, dst = wave-uniform base + lane*16
#define GLDS16(g, l) __builtin_amdgcn_global_load_lds( \
    (const __attribute__((address_space(1))) unsigned int*)(g), \
    (__attribute__((address_space(3))) unsigned int*)(l), 16, 0, 0)

// s_waitcnt imm (gfx9): vmcnt[3:0] | exp[6:4] | lgkm[11:8] | vmcnt_hi[15:14]
#define WAITCNT_VM(n)  (0x0F70 | (n))   // vmcnt(n), exp/lgkm no-wait (n<16)
#define WAITCNT_LGKM0  0xC07F           // lgkmcnt(0), vm/exp no-wait

// Problem: B=2, S=2048, D=1024, H=16, HD=64, M = B*S = 4096
// Softmax scale folded into Q at QKV epilogue: 0.125 * log2(e)
#define QSCALE 0.18033688f

// ---------------------------------------------------------------------------
// Fused conversion: local dtype-sniff per block (no extra dispatch), then
// X (2048 blocks) | weights (2048 blocks) | biases+flag (2 blocks).
// ---------------------------------------------------------------------------
__global__ __launch_bounds__(256) void cvt_all(
    const void* __restrict__ X,  const void* __restrict__ W0, const void* __restrict__ W1,
    const void* __restrict__ W2, const void* __restrict__ W3,
    const void* __restrict__ c0, const void* __restrict__ c1,
    const void* __restrict__ c2, const void* __restrict__ c3,
    bf16_t* __restrict__ Xb, bf16_t* __restrict__ Wb, float* __restrict__ biasF,
    int* __restrict__ flag)
{
    const int tid  = threadIdx.x;
    const int lane = tid & 63;
    // local sniff: even 16-bit halves of f32 X have junk-mantissa "exponents"
    const ushort_t u = ((const ushort_t*)X)[2 * lane];
    const int e = (u >> 7) & 0xFF;
    const int f = (__ballot(e >= 0xA0) != 0ull) ? 1 : 0;

    const int bid = blockIdx.x;
    if (bid >= 4096) {   // bias blocks
        if (bid == 4096 && tid == 0) *flag = f;
        const int idx = ((bid - 4096) * 256 + tid) * 8;   // 0..4095, chunks of 8
        const int w = idx >> 10, off = idx & 1023;
        const void* src = (w == 0) ? c0 : (w == 1) ? c1 : (w == 2) ? c2 : c3;
        #pragma unroll
        for (int r = 0; r < 8; ++r)
            biasF[idx + r] = f ? ((const float*)src)[off + r]
                               : (float)((const bf16_t*)src)[off + r];
        return;
    }

    const long long i = (long long)bid * 2048 + tid * 8;
    const void* src;
    bf16_t* dst;
    long long off;
    if (i < 4194304) { src = X; dst = Xb; off = i; }
    else {
        const int w = (int)((i - 4194304) >> 20);
        off = (i - 4194304) & 1048575;
        src = (w == 0) ? W0 : (w == 1) ? W1 : (w == 2) ? W2 : W3;
        dst = Wb + (size_t)w * 1048576;
    }
    if (f) {
        const float* s = (const float*)src + off;
        const float4 a = *(const float4*)(s);
        const float4 b = *(const float4*)(s + 4);
        bf16x8 o;
        o[0] = (bf16_t)a.x; o[1] = (bf16_t)a.y; o[2] = (bf16_t)a.z; o[3] = (bf16_t)a.w;
        o[4] = (bf16_t)b.x; o[5] = (bf16_t)b.y; o[6] = (bf16_t)b.z; o[7] = (bf16_t)b.w;
        *(bf16x8*)(dst + off) = o;
    } else {
        *(bf16x8*)(dst + off) = *(const bf16x8*)((const bf16_t*)src + off);
    }
}

// ---------------------------------------------------------------------------
// NT GEMM: C[m,n] = sum_k A[m,k]*W[n,k] + bias[n], K=1024.
// 128x128 tile, BK=32, 3-stage GLDS pipeline (prefetch 2 tiles, vmcnt(2G)).
// XOR swizzle blk^=(row>>1)&3 -> conflict-free ds_read_b128.
// fuse_vt: mat==2 (V) panel written TRANSPOSED to Vt[bh][d][s];
//          mat==0 (Q) panel written pre-scaled by QSCALE.
// NOTE (r8): TM=64 regressed 75 vs 53 us (MFMA/barrier halves) -> TM=128 only.
// ---------------------------------------------------------------------------
__global__ __launch_bounds__(256, 2) void gemm_nt(
    const bf16_t* __restrict__ A,
    const bf16_t* __restrict__ W0, const bf16_t* __restrict__ W1, const bf16_t* __restrict__ W2,
    const float* __restrict__ b0, const float* __restrict__ b1, const float* __restrict__ b2,
    void* __restrict__ C, int ldc, bf16_t* __restrict__ Vt, int fuse_vt,
    const int* __restrict__ flag, int is_out)
{
    __shared__ bf16_t Ash[3][128 * 32];
    __shared__ bf16_t Bsh[3][128 * 32];

    const int f32out = is_out ? *flag : 0;

    const int tid  = threadIdx.x;
    const int wid  = tid >> 6;
    const int lane = tid & 63;
    const int g    = lane >> 4;
    const int c    = lane & 15;

    const int m0  = blockIdx.x * 128;
    const int n0  = blockIdx.y * 128;
    const int mat = n0 >> 10;
    const bf16_t* W  = (mat == 0) ? W0 : (mat == 1) ? W1 : W2;
    const float*  bs = (mat == 0) ? b0 : (mat == 1) ? b1 : b2;
    const int nw = n0 & 1023;

    const int srow = lane >> 2;                        // 0..15
    const int sblk = (lane & 3) ^ ((lane >> 3) & 3);   // pre-swizzled source blk
    const bf16_t* Ag = A + (size_t)(m0 + wid * 32 + srow) * 1024 + sblk * 8;
    const bf16_t* Wg = W + (size_t)(nw + wid * 32 + srow) * 1024 + sblk * 8;

    const int waveM = (wid >> 1) * 64;
    const int waveN = (wid & 1) * 64;

    f32x4 acc[4][4] = {};
    const int fblk = (g ^ ((c >> 1) & 3)) * 8;

    auto stage = [&](int t, int buf) {
        const int k0 = t * 32;
        bf16_t* As = &Ash[buf][(wid * 32) * 32];
        bf16_t* Bs = &Bsh[buf][(wid * 32) * 32];
        GLDS16(Ag + k0, As);
        GLDS16(Ag + (size_t)16 * 1024 + k0, As + 16 * 32);
        GLDS16(Wg + k0, Bs);
        GLDS16(Wg + (size_t)16 * 1024 + k0, Bs + 16 * 32);
    };

    stage(0, 0);
    stage(1, 1);

    #pragma unroll 3
    for (int k = 0; k < 32; ++k) {
        if (k < 30) {
            stage(k + 2, (k + 2) % 3);
            __builtin_amdgcn_s_waitcnt(WAITCNT_VM(8));   // tile k's 4 done
        } else if (k == 30) {
            __builtin_amdgcn_s_waitcnt(WAITCNT_VM(4));
        } else {
            __builtin_amdgcn_s_waitcnt(WAITCNT_VM(0));
        }
        __builtin_amdgcn_s_barrier();
        asm volatile("" ::: "memory");

        const int cur = k % 3;
        bf16x8 af[4], bfr[4];
        #pragma unroll
        for (int i = 0; i < 4; ++i)
            af[i] = *(const bf16x8*)(&Ash[cur][(waveM + i * 16 + c) * 32 + fblk]);
        #pragma unroll
        for (int j = 0; j < 4; ++j)
            bfr[j] = *(const bf16x8*)(&Bsh[cur][(waveN + j * 16 + c) * 32 + fblk]);
        #pragma unroll
        for (int i = 0; i < 4; ++i)
            #pragma unroll
            for (int j = 0; j < 4; ++j)
                acc[i][j] = MFMA16(af[i], bfr[j], acc[i][j]);

        asm volatile("" ::: "memory");
        __builtin_amdgcn_s_waitcnt(WAITCNT_LGKM0);  // my LDS reads done
        __builtin_amdgcn_s_barrier();               // buf free for restage
    }

    if (fuse_vt && mat == 2) {
        // write V^T: Vt[((b*16+h)*64 + d)*2048 + s]; 4 consecutive s per store
        #pragma unroll
        for (int j = 0; j < 4; ++j) {
            const int col  = n0 + waveN + j * 16 + c;
            const int hcol = col & 1023;
            const float bv = bs[hcol];
            const int h = hcol >> 6, d = hcol & 63;
            #pragma unroll
            for (int i = 0; i < 4; ++i) {
                const int row = m0 + waveM + i * 16 + g * 4;
                const int bb = row >> 11, s = row & 2047;
                bf16_t pk[4];
                #pragma unroll
                for (int r = 0; r < 4; ++r) pk[r] = (bf16_t)(acc[i][j][r] + bv);
                *(uint2*)(&Vt[(((size_t)bb * 16 + h) * 64 + d) * 2048 + s]) = *(uint2*)pk;
            }
        }
        return;
    }

    const float oscale = (fuse_vt && mat == 0) ? QSCALE : 1.0f;  // pre-scale Q
    #pragma unroll
    for (int j = 0; j < 4; ++j) {
        const int col = n0 + waveN + j * 16 + c;
        const float bv = bs[col & 1023];
        #pragma unroll
        for (int i = 0; i < 4; ++i) {
            const int row = m0 + waveM + i * 16 + g * 4;
            #pragma unroll
            for (int r = 0; r < 4; ++r) {
                const float val = (acc[i][j][r] + bv) * oscale;
                const size_t idx = (size_t)(row + r) * ldc + col;
                if (f32out) ((float*)C)[idx] = val;
                else        ((bf16_t*)C)[idx] = (bf16_t)val;
            }
        }
    }
}

// ---------------------------------------------------------------------------
// Causal flash attention, no-max softmax in exp2 domain (scale pre-folded
// into Q at the QKV epilogue). 64 Q rows/block, 4 waves x 16 rows; 64-key
// tiles; K/V register prefetch. 27KB LDS -> 5 blocks/CU.
// Dispatch-order balance: qt interleaved small/large so temporally adjacent
// blocks pair to 33 tiles (x-major dispatch would otherwise leave a qt=31
// straggler tail).
// ---------------------------------------------------------------------------
__global__ __launch_bounds__(256, 4) void attn_kernel(
    const bf16_t* __restrict__ QKV, const bf16_t* __restrict__ Vt,
    bf16_t* __restrict__ O)
{
    __shared__ bf16_t Ksh[64][72];
    __shared__ bf16_t Vsh[64][72];
    __shared__ bf16_t Psh[4][16][72];

    const int tid  = threadIdx.x;
    const int wid  = tid >> 6;
    const int lane = tid & 63;
    const int g    = lane >> 4;
    const int c    = lane & 15;

    const int bh = blockIdx.y;
    const int b  = bh >> 4, h = bh & 15;
    const int x  = blockIdx.x;
    const int qt = (x & 1) ? (31 - (x >> 1)) : (x >> 1);
    const int q0 = qt * 64;
    const int nt = qt + 1;   // # of 64-key tiles

    // Q A-frags (already scaled by QSCALE at the QKV epilogue)
    bf16x8 aq[2];
    {
        const bf16_t* qp = QKV + (size_t)(b * 2048 + q0 + wid * 16 + c) * 3072 + h * 64;
        aq[0] = *(const bf16x8*)(qp + g * 8);
        aq[1] = *(const bf16x8*)(qp + 32 + g * 8);
    }

    float li[4] = {};
    f32x4 o[4]  = {};

    const int sr  = tid >> 2;
    const int sc0 = (tid & 3) * 16;
    const bf16_t* Kg = QKV + (size_t)(b * 2048 + sr) * 3072 + 1024 + h * 64 + sc0;
    const bf16_t* Vg = Vt + ((size_t)bh * 64 + sr) * 2048 + sc0;

    uint4 kr0 = *(const uint4*)(Kg);
    uint4 kr1 = *(const uint4*)(Kg + 8);
    uint4 vr0 = *(const uint4*)(Vg);
    uint4 vr1 = *(const uint4*)(Vg + 8);

    for (int jt = 0; jt < nt; ++jt) {
        *(uint4*)(&Ksh[sr][sc0])     = kr0;
        *(uint4*)(&Ksh[sr][sc0 + 8]) = kr1;
        *(uint4*)(&Vsh[sr][sc0])     = vr0;
        *(uint4*)(&Vsh[sr][sc0 + 8]) = vr1;
        __syncthreads();

        if (jt + 1 < nt) {
            const size_t ko = (size_t)(jt + 1) * 64 * 3072;
            kr0 = *(const uint4*)(Kg + ko);
            kr1 = *(const uint4*)(Kg + ko + 8);
            vr0 = *(const uint4*)(Vg + (jt + 1) * 64);
            vr1 = *(const uint4*)(Vg + (jt + 1) * 64 + 8);
        }

        f32x4 s[4] = {};
        #pragma unroll
        for (int n = 0; n < 4; ++n)
            #pragma unroll
            for (int kb = 0; kb < 2; ++kb) {
                const bf16x8 kf = *(const bf16x8*)(&Ksh[n * 16 + c][kb * 32 + g * 8]);
                s[n] = MFMA16(aq[kb], kf, s[n]);
            }

        if (jt == nt - 1) {   // diagonal tile
            const int j0 = jt * 64;
            const int qrow = q0 + wid * 16 + g * 4;
            #pragma unroll
            for (int n = 0; n < 4; ++n)
                #pragma unroll
                for (int r = 0; r < 4; ++r)
                    if (j0 + n * 16 + c > qrow + r) s[n][r] = -1e30f;
        }

        #pragma unroll
        for (int n = 0; n < 4; ++n)
            #pragma unroll
            for (int r = 0; r < 4; ++r) {
                const float p = __builtin_amdgcn_exp2f(s[n][r]);
                li[r] += p;
                Psh[wid][g * 4 + r][n * 16 + c] = (bf16_t)p;
            }
        __builtin_amdgcn_wave_barrier();   // Psh wave-private; DS in-order

        #pragma unroll
        for (int kb = 0; kb < 2; ++kb) {
            const bf16x8 ap = *(const bf16x8*)(&Psh[wid][c][kb * 32 + g * 8]);
            #pragma unroll
            for (int d = 0; d < 4; ++d) {
                const bf16x8 vf = *(const bf16x8*)(&Vsh[d * 16 + c][kb * 32 + g * 8]);
                o[d] = MFMA16(ap, vf, o[d]);
            }
        }
        __syncthreads();
    }

    #pragma unroll
    for (int off = 1; off < 16; off <<= 1)
        #pragma unroll
        for (int r = 0; r < 4; ++r)
            li[r] += __shfl_xor(li[r], off, 64);

    const int orow = b * 2048 + q0 + wid * 16 + g * 4;
    #pragma unroll
    for (int r = 0; r < 4; ++r) {
        const float inv = 1.0f / li[r];
        #pragma unroll
        for (int d = 0; d < 4; ++d)
            O[(size_t)(orow + r) * 1024 + h * 64 + d * 16 + c] = (bf16_t)(o[d][r] * inv);
    }
}

// ---------------------------------------------------------------------------
extern "C" void kernel_launch(void* const* d_in, const int* in_sizes, int n_in,
                              void* d_out, int out_size, void* d_ws, size_t ws_size,
                              hipStream_t stream)
{
    const void* X  = d_in[0];
    const void* Wq = d_in[1];  const void* bq = d_in[2];
    const void* Wk = d_in[3];  const void* bk = d_in[4];
    const void* Wv = d_in[5];  const void* bv = d_in[6];
    const void* Wo = d_in[7];  const void* bo = d_in[8];

    int*    flag  = (int*)d_ws;
    float*  biasF = (float*)((char*)d_ws + 16);              // [4][1024]
    bf16_t* Xb    = (bf16_t*)((char*)d_ws + 16 + 16384);     // 4096x1024
    bf16_t* Wb    = Xb  + (size_t)4096 * 1024;               // 4x 1024x1024 (q,k,v,o)
    bf16_t* QKV   = Wb  + (size_t)4 * 1024 * 1024;           // 4096x3072 (V cols unused)
    bf16_t* Vt    = QKV + (size_t)4096 * 3072;               // 32x64x2048
    bf16_t* Ao    = Vt  + (size_t)4096 * 1024;               // 4096x1024

    const size_t MW = (size_t)1024 * 1024;

    cvt_all<<<4098, 256, 0, stream>>>(X, Wq, Wk, Wv, Wo, bq, bk, bv, bo,
                                      Xb, Wb, biasF, flag);

    gemm_nt<<<dim3(32, 24), 256, 0, stream>>>(
        Xb, Wb, Wb + MW, Wb + 2 * MW,
        biasF, biasF + 1024, biasF + 2048, QKV, 3072, Vt, 1, flag, 0);
    attn_kernel<<<dim3(32, 32), 256, 0, stream>>>(QKV, Vt, Ao);
    gemm_nt<<<dim3(32, 8), 256, 0, stream>>>(
        Ao, Wb + 3 * MW, Wb + 3 * MW, Wb + 3 * MW,
        biasF + 3072, biasF + 3072, biasF + 3072, d_out, 1024, (bf16_t*)nullptr, 0, flag, 1);
}

// Round 11
// 200.814 us; speedup vs baseline: 1.1416x; 1.1416x over previous
//
#include <hip/hip_runtime.h>
#include <hip/hip_bf16.h>

typedef __bf16 bf16_t;
typedef __bf16 bf16x8 __attribute__((ext_vector_type(8)));
typedef float  f32x4  __attribute__((ext_vector_type(4)));
typedef unsigned short ushort_t;

#define MFMA16(a, b, c) __builtin_amdgcn_mfma_f32_16x16x32_bf16((a), (b), (c), 0, 0, 0)
// async global->LDS, 16B/lane, dst = wave-uniform base + lane*16
#define GLDS16(g, l) __builtin_amdgcn_global_load_lds( \
    (const __attribute__((address_space(1))) unsigned int*)(g), \
    (__attribute__((address_space(3))) unsigned int*)(l), 16, 0, 0)

// s_waitcnt imm (gfx9): vmcnt[3:0] | exp[6:4] | lgkm[11:8] | vmcnt_hi[15:14]
#define WAITCNT_VM(n)  (0x0F70 | (n))   // vmcnt(n), exp/lgkm no-wait (n<16)
#define WAITCNT_LGKM0  0xC07F           // lgkmcnt(0), vm/exp no-wait

// Problem: B=2, S=2048, D=1024, H=16, HD=64, M = B*S = 4096
// Softmax scale folded into Q at QKV epilogue: 0.125 * log2(e)
#define QSCALE 0.18033688f

// ---------------------------------------------------------------------------
// Fused conversion: local dtype-sniff per block (no extra dispatch), then
// X (2048 blocks) | weights (2048 blocks) | biases+flag (2 blocks).
// ---------------------------------------------------------------------------
__global__ __launch_bounds__(256) void cvt_all(
    const void* __restrict__ X,  const void* __restrict__ W0, const void* __restrict__ W1,
    const void* __restrict__ W2, const void* __restrict__ W3,
    const void* __restrict__ c0, const void* __restrict__ c1,
    const void* __restrict__ c2, const void* __restrict__ c3,
    bf16_t* __restrict__ Xb, bf16_t* __restrict__ Wb, float* __restrict__ biasF,
    int* __restrict__ flag)
{
    const int tid  = threadIdx.x;
    const int lane = tid & 63;
    // local sniff: even 16-bit halves of f32 X have junk-mantissa "exponents"
    const ushort_t u = ((const ushort_t*)X)[2 * lane];
    const int e = (u >> 7) & 0xFF;
    const int f = (__ballot(e >= 0xA0) != 0ull) ? 1 : 0;

    const int bid = blockIdx.x;
    if (bid >= 4096) {   // bias blocks
        if (bid == 4096 && tid == 0) *flag = f;
        const int idx = ((bid - 4096) * 256 + tid) * 8;   // 0..4095, chunks of 8
        const int w = idx >> 10, off = idx & 1023;
        const void* src = (w == 0) ? c0 : (w == 1) ? c1 : (w == 2) ? c2 : c3;
        #pragma unroll
        for (int r = 0; r < 8; ++r)
            biasF[idx + r] = f ? ((const float*)src)[off + r]
                               : (float)((const bf16_t*)src)[off + r];
        return;
    }

    const long long i = (long long)bid * 2048 + tid * 8;
    const void* src;
    bf16_t* dst;
    long long off;
    if (i < 4194304) { src = X; dst = Xb; off = i; }
    else {
        const int w = (int)((i - 4194304) >> 20);
        off = (i - 4194304) & 1048575;
        src = (w == 0) ? W0 : (w == 1) ? W1 : (w == 2) ? W2 : W3;
        dst = Wb + (size_t)w * 1048576;
    }
    if (f) {
        const float* s = (const float*)src + off;
        const float4 a = *(const float4*)(s);
        const float4 b = *(const float4*)(s + 4);
        bf16x8 o;
        o[0] = (bf16_t)a.x; o[1] = (bf16_t)a.y; o[2] = (bf16_t)a.z; o[3] = (bf16_t)a.w;
        o[4] = (bf16_t)b.x; o[5] = (bf16_t)b.y; o[6] = (bf16_t)b.z; o[7] = (bf16_t)b.w;
        *(bf16x8*)(dst + off) = o;
    } else {
        *(bf16x8*)(dst + off) = *(const bf16x8*)((const bf16_t*)src + off);
    }
}

// ---------------------------------------------------------------------------
// NT GEMM: C[m,n] = sum_k A[m,k]*W[n,k] + bias[n], K=1024.
// TM x 128 tile, BK=32, 3-stage GLDS pipeline (prefetch 2 tiles, vmcnt(2G)).
// XOR swizzle blk^=(row>>1)&3 -> conflict-free ds_read_b128.
// fuse_vt: mat==2 (V) panel written TRANSPOSED to Vt[bh][d][s];
//          mat==0 (Q) panel written pre-scaled by QSCALE.
// NOTE (r8): TM=64 on the big QKV GEMM regressed 75 vs 53 us (MFMA/barrier
// halves) -> TM=128 there. TM=64 for out-proj (N=1024 -> needs 512 blocks;
// r10's TM=128 grid(32,8)=1 block/CU regressed).
// ---------------------------------------------------------------------------
template<int TM>
__global__ __launch_bounds__(256, 2) void gemm_nt(
    const bf16_t* __restrict__ A,
    const bf16_t* __restrict__ W0, const bf16_t* __restrict__ W1, const bf16_t* __restrict__ W2,
    const float* __restrict__ b0, const float* __restrict__ b1, const float* __restrict__ b2,
    void* __restrict__ C, int ldc, bf16_t* __restrict__ Vt, int fuse_vt,
    const int* __restrict__ flag, int is_out)
{
    constexpr int MI = TM / 32;              // acc frags in M per wave
    constexpr int G  = (TM == 128) ? 4 : 3;  // GLDS per wave per tile
    __shared__ bf16_t Ash[3][TM * 32];
    __shared__ bf16_t Bsh[3][128 * 32];

    const int f32out = is_out ? *flag : 0;

    const int tid  = threadIdx.x;
    const int wid  = tid >> 6;
    const int lane = tid & 63;
    const int g    = lane >> 4;
    const int c    = lane & 15;

    const int m0  = blockIdx.x * TM;
    const int n0  = blockIdx.y * 128;
    const int mat = n0 >> 10;
    const bf16_t* W  = (mat == 0) ? W0 : (mat == 1) ? W1 : W2;
    const float*  bs = (mat == 0) ? b0 : (mat == 1) ? b1 : b2;
    const int nw = n0 & 1023;

    const int srow = lane >> 2;                        // 0..15
    const int sblk = (lane & 3) ^ ((lane >> 3) & 3);   // pre-swizzled source blk
    const bf16_t* Ag = A + (size_t)(m0 + wid * (TM / 4) + srow) * 1024 + sblk * 8;
    const bf16_t* Wg = W + (size_t)(nw + wid * 32 + srow) * 1024 + sblk * 8;

    const int waveM = (wid >> 1) * (TM / 2);
    const int waveN = (wid & 1) * 64;

    f32x4 acc[MI][4] = {};
    const int fblk = (g ^ ((c >> 1) & 3)) * 8;

    auto stage = [&](int t, int buf) {
        const int k0 = t * 32;
        bf16_t* As = &Ash[buf][(wid * (TM / 4)) * 32];
        bf16_t* Bs = &Bsh[buf][(wid * 32) * 32];
        GLDS16(Ag + k0, As);
        if (TM == 128) GLDS16(Ag + (size_t)16 * 1024 + k0, As + 16 * 32);
        GLDS16(Wg + k0, Bs);
        GLDS16(Wg + (size_t)16 * 1024 + k0, Bs + 16 * 32);
    };

    stage(0, 0);
    stage(1, 1);

    #pragma unroll 3
    for (int k = 0; k < 32; ++k) {
        if (k < 30) {
            stage(k + 2, (k + 2) % 3);
            __builtin_amdgcn_s_waitcnt(WAITCNT_VM(2 * G));  // tile k done
        } else if (k == 30) {
            __builtin_amdgcn_s_waitcnt(WAITCNT_VM(G));
        } else {
            __builtin_amdgcn_s_waitcnt(WAITCNT_VM(0));
        }
        __builtin_amdgcn_s_barrier();
        asm volatile("" ::: "memory");

        const int cur = k % 3;
        bf16x8 af[MI], bfr[4];
        #pragma unroll
        for (int i = 0; i < MI; ++i)
            af[i] = *(const bf16x8*)(&Ash[cur][(waveM + i * 16 + c) * 32 + fblk]);
        #pragma unroll
        for (int j = 0; j < 4; ++j)
            bfr[j] = *(const bf16x8*)(&Bsh[cur][(waveN + j * 16 + c) * 32 + fblk]);
        #pragma unroll
        for (int i = 0; i < MI; ++i)
            #pragma unroll
            for (int j = 0; j < 4; ++j)
                acc[i][j] = MFMA16(af[i], bfr[j], acc[i][j]);

        asm volatile("" ::: "memory");
        __builtin_amdgcn_s_waitcnt(WAITCNT_LGKM0);  // my LDS reads done
        __builtin_amdgcn_s_barrier();               // buf free for restage
    }

    if (fuse_vt && mat == 2) {
        // write V^T: Vt[((b*16+h)*64 + d)*2048 + s]; 4 consecutive s per store
        #pragma unroll
        for (int j = 0; j < 4; ++j) {
            const int col  = n0 + waveN + j * 16 + c;
            const int hcol = col & 1023;
            const float bv = bs[hcol];
            const int h = hcol >> 6, d = hcol & 63;
            #pragma unroll
            for (int i = 0; i < MI; ++i) {
                const int row = m0 + waveM + i * 16 + g * 4;
                const int bb = row >> 11, s = row & 2047;
                bf16_t pk[4];
                #pragma unroll
                for (int r = 0; r < 4; ++r) pk[r] = (bf16_t)(acc[i][j][r] + bv);
                *(uint2*)(&Vt[(((size_t)bb * 16 + h) * 64 + d) * 2048 + s]) = *(uint2*)pk;
            }
        }
        return;
    }

    const float oscale = (fuse_vt && mat == 0) ? QSCALE : 1.0f;  // pre-scale Q
    #pragma unroll
    for (int j = 0; j < 4; ++j) {
        const int col = n0 + waveN + j * 16 + c;
        const float bv = bs[col & 1023];
        #pragma unroll
        for (int i = 0; i < MI; ++i) {
            const int row = m0 + waveM + i * 16 + g * 4;
            #pragma unroll
            for (int r = 0; r < 4; ++r) {
                const float val = (acc[i][j][r] + bv) * oscale;
                const size_t idx = (size_t)(row + r) * ldc + col;
                if (f32out) ((float*)C)[idx] = val;
                else        ((bf16_t*)C)[idx] = (bf16_t)val;
            }
        }
    }
}

// ---------------------------------------------------------------------------
// Causal flash attention, no-max softmax in exp2 domain (scale pre-folded
// into Q at the QKV epilogue). 64 Q rows/block, 4 waves x 16 rows; 64-key
// tiles; K/V register prefetch. 27KB LDS -> 5 blocks/CU (4 resident here).
// qt mapping: bh-mirror. With linear block->CU assignment (i mod 256,
// 256 == 0 mod 32) each CU sees fixed x with two y<16 and two y>=16 blocks
// -> per-CU work = 2*(x+1) + 2*(32-x) = 66 tiles, CONSTANT. (r10's x-based
// interleave put equal-qt blocks on the same CU: 32:1 imbalance, +16 us.)
// ---------------------------------------------------------------------------
__global__ __launch_bounds__(256, 4) void attn_kernel(
    const bf16_t* __restrict__ QKV, const bf16_t* __restrict__ Vt,
    bf16_t* __restrict__ O)
{
    __shared__ bf16_t Ksh[64][72];
    __shared__ bf16_t Vsh[64][72];
    __shared__ bf16_t Psh[4][16][72];

    const int tid  = threadIdx.x;
    const int wid  = tid >> 6;
    const int lane = tid & 63;
    const int g    = lane >> 4;
    const int c    = lane & 15;

    const int bh = blockIdx.y;
    const int b  = bh >> 4, h = bh & 15;
    const int qt = (bh < 16) ? blockIdx.x : (31 - blockIdx.x);
    const int q0 = qt * 64;
    const int nt = qt + 1;   // # of 64-key tiles

    // Q A-frags (already scaled by QSCALE at the QKV epilogue)
    bf16x8 aq[2];
    {
        const bf16_t* qp = QKV + (size_t)(b * 2048 + q0 + wid * 16 + c) * 3072 + h * 64;
        aq[0] = *(const bf16x8*)(qp + g * 8);
        aq[1] = *(const bf16x8*)(qp + 32 + g * 8);
    }

    float li[4] = {};
    f32x4 o[4]  = {};

    const int sr  = tid >> 2;
    const int sc0 = (tid & 3) * 16;
    const bf16_t* Kg = QKV + (size_t)(b * 2048 + sr) * 3072 + 1024 + h * 64 + sc0;
    const bf16_t* Vg = Vt + ((size_t)bh * 64 + sr) * 2048 + sc0;

    uint4 kr0 = *(const uint4*)(Kg);
    uint4 kr1 = *(const uint4*)(Kg + 8);
    uint4 vr0 = *(const uint4*)(Vg);
    uint4 vr1 = *(const uint4*)(Vg + 8);

    for (int jt = 0; jt < nt; ++jt) {
        *(uint4*)(&Ksh[sr][sc0])     = kr0;
        *(uint4*)(&Ksh[sr][sc0 + 8]) = kr1;
        *(uint4*)(&Vsh[sr][sc0])     = vr0;
        *(uint4*)(&Vsh[sr][sc0 + 8]) = vr1;
        __syncthreads();

        if (jt + 1 < nt) {
            const size_t ko = (size_t)(jt + 1) * 64 * 3072;
            kr0 = *(const uint4*)(Kg + ko);
            kr1 = *(const uint4*)(Kg + ko + 8);
            vr0 = *(const uint4*)(Vg + (jt + 1) * 64);
            vr1 = *(const uint4*)(Vg + (jt + 1) * 64 + 8);
        }

        f32x4 s[4] = {};
        #pragma unroll
        for (int n = 0; n < 4; ++n)
            #pragma unroll
            for (int kb = 0; kb < 2; ++kb) {
                const bf16x8 kf = *(const bf16x8*)(&Ksh[n * 16 + c][kb * 32 + g * 8]);
                s[n] = MFMA16(aq[kb], kf, s[n]);
            }

        if (jt == nt - 1) {   // diagonal tile
            const int j0 = jt * 64;
            const int qrow = q0 + wid * 16 + g * 4;
            #pragma unroll
            for (int n = 0; n < 4; ++n)
                #pragma unroll
                for (int r = 0; r < 4; ++r)
                    if (j0 + n * 16 + c > qrow + r) s[n][r] = -1e30f;
        }

        #pragma unroll
        for (int n = 0; n < 4; ++n)
            #pragma unroll
            for (int r = 0; r < 4; ++r) {
                const float p = __builtin_amdgcn_exp2f(s[n][r]);
                li[r] += p;
                Psh[wid][g * 4 + r][n * 16 + c] = (bf16_t)p;
            }
        __builtin_amdgcn_wave_barrier();   // Psh wave-private; DS in-order

        #pragma unroll
        for (int kb = 0; kb < 2; ++kb) {
            const bf16x8 ap = *(const bf16x8*)(&Psh[wid][c][kb * 32 + g * 8]);
            #pragma unroll
            for (int d = 0; d < 4; ++d) {
                const bf16x8 vf = *(const bf16x8*)(&Vsh[d * 16 + c][kb * 32 + g * 8]);
                o[d] = MFMA16(ap, vf, o[d]);
            }
        }
        __syncthreads();
    }

    #pragma unroll
    for (int off = 1; off < 16; off <<= 1)
        #pragma unroll
        for (int r = 0; r < 4; ++r)
            li[r] += __shfl_xor(li[r], off, 64);

    const int orow = b * 2048 + q0 + wid * 16 + g * 4;
    #pragma unroll
    for (int r = 0; r < 4; ++r) {
        const float inv = 1.0f / li[r];
        #pragma unroll
        for (int d = 0; d < 4; ++d)
            O[(size_t)(orow + r) * 1024 + h * 64 + d * 16 + c] = (bf16_t)(o[d][r] * inv);
    }
}

// ---------------------------------------------------------------------------
extern "C" void kernel_launch(void* const* d_in, const int* in_sizes, int n_in,
                              void* d_out, int out_size, void* d_ws, size_t ws_size,
                              hipStream_t stream)
{
    const void* X  = d_in[0];
    const void* Wq = d_in[1];  const void* bq = d_in[2];
    const void* Wk = d_in[3];  const void* bk = d_in[4];
    const void* Wv = d_in[5];  const void* bv = d_in[6];
    const void* Wo = d_in[7];  const void* bo = d_in[8];

    int*    flag  = (int*)d_ws;
    float*  biasF = (float*)((char*)d_ws + 16);              // [4][1024]
    bf16_t* Xb    = (bf16_t*)((char*)d_ws + 16 + 16384);     // 4096x1024
    bf16_t* Wb    = Xb  + (size_t)4096 * 1024;               // 4x 1024x1024 (q,k,v,o)
    bf16_t* QKV   = Wb  + (size_t)4 * 1024 * 1024;           // 4096x3072 (V cols unused)
    bf16_t* Vt    = QKV + (size_t)4096 * 3072;               // 32x64x2048
    bf16_t* Ao    = Vt  + (size_t)4096 * 1024;               // 4096x1024

    const size_t MW = (size_t)1024 * 1024;

    cvt_all<<<4098, 256, 0, stream>>>(X, Wq, Wk, Wv, Wo, bq, bk, bv, bo,
                                      Xb, Wb, biasF, flag);

    gemm_nt<128><<<dim3(32, 24), 256, 0, stream>>>(
        Xb, Wb, Wb + MW, Wb + 2 * MW,
        biasF, biasF + 1024, biasF + 2048, QKV, 3072, Vt, 1, flag, 0);
    attn_kernel<<<dim3(32, 32), 256, 0, stream>>>(QKV, Vt, Ao);
    gemm_nt<64><<<dim3(64, 8), 256, 0, stream>>>(
        Ao, Wb + 3 * MW, Wb + 3 * MW, Wb + 3 * MW,
        biasF + 3072, biasF + 3072, biasF + 3072, d_out, 1024, (bf16_t*)nullptr, 0, flag, 1);
}